// Round 21
// baseline (166.786 us; speedup 1.0000x reference)
//
#include <hip/hip_runtime.h>
#include <hip/hip_bf16.h>
#include <stdint.h>

#define B_  32
#define L_  512
#define D_  256
#define K_  65
#define FROW 80        // F-matrix row stride in BYTES (fp8), 16B-divisible
#define FMB  5200      // bytes per fp8 F matrix (65*80)
#define NP3  5248      // padded GEMM N: 41*128 (n = 80*i + j)
#define M_   16384     // B_*L_
#define MROW 72        // chunkOut row stride (bf16 elems)
#define MELEM 4680     // 65*72 elems per bf16 matrix
#define MBYTE 9360     // bytes per bf16 matrix
#define CB0  12288     // chain0 LDS bytes per buffer (96*128)
#define LMAT2 12288    // chain1 LDS elems per buffer (96*128 bf16)
#define GBYTE 24576    // chain1 LDS bytes per buffer

typedef __attribute__((ext_vector_type(8))) short bf16x8;
typedef __attribute__((ext_vector_type(4))) float f32x4;
typedef long long i64;

typedef unsigned int u32g __attribute__((address_space(1)));
typedef unsigned int u32l __attribute__((address_space(3)));

__device__ __forceinline__ void async_ld16(const void* g, void* l) {
  __builtin_amdgcn_global_load_lds((const u32g*)g, (u32l*)l, 16, 0, 0);
}

// bare v_exp_f32 (2^x): single trans-pipe instruction, no OCML range wrapper.
// Args here are bounded (|x| < ~70), denormal flush is fine (fp8 target).
__device__ __forceinline__ float fast_exp2(float x) {
  float r;
  asm("v_exp_f32 %0, %1" : "=v"(r) : "v"(x));
  return r;
}

// fp8 chain LDS [96 rows][128 B]: 16B-atom XOR swizzle; c = byte col 0..95
__device__ __forceinline__ int swz8(int row, int c) {
  return row * 128 + (c & 15) + ((((c >> 4) ^ row) & 7) << 4);
}
// bf16 chain LDS [96][128 elems]
__device__ __forceinline__ int swzc(int row, int col) {
  return row * 128 + (col & 7) + ((((col >> 3) ^ row) & 15) << 3);
}
// gemm LDS [128][64 elems]
__device__ __forceinline__ int swzg(int row, int col) {
  return row * 64 + ((col & 7) | ((((col >> 3) ^ row) & 7) << 3));
}

// ---------------- prep (fused): W-pack + x-pack + exact tgt score ----------
__global__ __launch_bounds__(256) void prep_kernel(
    const float* __restrict__ x, const float* __restrict__ Ws,
    const float* __restrict__ bs, const float* __restrict__ Wt,
    const float* __restrict__ bt, const int* __restrict__ target,
    const float* __restrict__ mask,
    __hip_bfloat16* __restrict__ wbf, float* __restrict__ bias,
    uint* __restrict__ zreg,
    __hip_bfloat16* __restrict__ xbf, float* __restrict__ tgtE) {
  if (blockIdx.x < NP3) {
    // ---- W'[n=80i+j] = Wt[i*65+j] + Ws[j]; pad bias = -1e30 ----
    int n = blockIdx.x, d = threadIdx.x;
    int i = n / 80, j = n - i * 80;
    bool valid = (j < K_) && (i < K_);
    float v = 0.f;
    if (valid) v = Wt[(size_t)(i * 65 + j) * D_ + d] + Ws[(size_t)j * D_ + d];
    wbf[(size_t)n * D_ + d] = __float2bfloat16(v);
    if (d == 0) bias[n] = valid ? (bt[i * 65 + j] + bs[j]) : -1e30f;
    if (n == 0 && d < 64) zreg[d] = 0u;
  } else {
    // ---- x -> bf16 + fused tgt-path score (one wave per (b,t) row) ----
    int wid = threadIdx.x >> 6, lane = threadIdx.x & 63;
    int row = (blockIdx.x - NP3) * 4 + wid;  // 0..M_-1
    int t = row & 511;
    float4 xx = ((const float4*)x)[row * 64 + lane];
    __hip_bfloat16 o[4] = {__float2bfloat16(xx.x), __float2bfloat16(xx.y),
                           __float2bfloat16(xx.z), __float2bfloat16(xx.w)};
    *(uint2*)(xbf + (size_t)row * D_ + lane * 4) = *(const uint2*)o;

    int y = target[row];
    int prev = (t == 0) ? (K_ - 1) : target[row - 1];
    int p = prev * 65 + y;
    float4 aa = ((const float4*)(Wt + (size_t)p * D_))[lane];
    float4 cc = ((const float4*)(Ws + (size_t)y * D_))[lane];
    float acc = xx.x * (aa.x + cc.x) + xx.y * (aa.y + cc.y) +
                xx.z * (aa.z + cc.z) + xx.w * (aa.w + cc.w);
#pragma unroll
    for (int o2 = 32; o2; o2 >>= 1) acc += __shfl_xor(acc, o2);
    if (lane == 0) tgtE[row] = (acc + bt[p] + bs[y]) * mask[row];
  }
}

// ---------------- GEMM: F = fp8( 2^-5 * exp((A*B^T + bias) * mask) ) -------
// F fp8 matrices t=1..511 at m = b*511+(t-1), 80-B rows; t=0 row64 -> p0buf
__global__ __launch_bounds__(256) void gemm_exp_kernel(
    const __hip_bfloat16* __restrict__ A, const __hip_bfloat16* __restrict__ Bm,
    const float* __restrict__ bias, const float* __restrict__ mask,
    char* __restrict__ F, char* __restrict__ p0buf) {
  __shared__ __align__(16) char shm[32768];  // K-loop: As|Bs ; epilogue: Ep[128][144]
  __hip_bfloat16* As = (__hip_bfloat16*)shm;
  __hip_bfloat16* Bs = (__hip_bfloat16*)(shm + 16384);
  int tid = threadIdx.x;
  // XCD-aware swizzle of the flattened 5248-block grid (5248 = 8 * 656)
  int bid = blockIdx.y * 128 + blockIdx.x;
  int swz = (bid & 7) * 656 + (bid >> 3);
  int mBase = (swz & 127) * 128;
  int nBase = (swz >> 7) * 128;
  int wid = tid >> 6, lane = tid & 63;
  int wm = (wid >> 1) * 64, wn = (wid & 1) * 64;
  int lrow = lane & 15, lk = (lane >> 4) * 8;

  f32x4 acc[4][4];
#pragma unroll
  for (int a = 0; a < 4; ++a)
#pragma unroll
    for (int c = 0; c < 4; ++c) acc[a][c] = (f32x4){0.f, 0.f, 0.f, 0.f};

  int gsrc = (((tid & 7) ^ ((tid >> 3) & 7))) * 8;
  const __hip_bfloat16* aSrc = A + (size_t)(mBase + (tid >> 3)) * D_ + gsrc;
  const __hip_bfloat16* bSrc = Bm + (size_t)(nBase + (tid >> 3)) * D_ + gsrc;
  char* aDst = shm + tid * 16;
  char* bDst = shm + 16384 + tid * 16;

  for (int kt = 0; kt < D_; kt += 64) {
#pragma unroll
    for (int i = 0; i < 4; ++i) {
      async_ld16(aSrc + (size_t)i * 32 * D_ + kt, aDst + i * 4096);
      async_ld16(bSrc + (size_t)i * 32 * D_ + kt, bDst + i * 4096);
    }
    __syncthreads();
#pragma unroll
    for (int kk = 0; kk < 64; kk += 32) {
      bf16x8 af[4], bfr[4];
#pragma unroll
      for (int f = 0; f < 4; ++f) {
        af[f]  = *(const bf16x8*)(As + swzg(wm + f * 16 + lrow, kk + lk));
        bfr[f] = *(const bf16x8*)(Bs + swzg(wn + f * 16 + lrow, kk + lk));
      }
      __builtin_amdgcn_s_setprio(1);
#pragma unroll
      for (int fm = 0; fm < 4; ++fm)
#pragma unroll
        for (int fn = 0; fn < 4; ++fn)
          acc[fm][fn] = __builtin_amdgcn_mfma_f32_16x16x32_bf16(
              af[fm], bfr[fn], acc[fm][fn], 0, 0, 0);
      __builtin_amdgcn_s_setprio(0);
    }
    __syncthreads();
  }

  // ---- phase 1: fp8 epilogue -> LDS Ep[128][144] ----
  char* Ep = shm;
  char* ep0 = Ep + (wm + (lane >> 4) * 4) * 144 + wn + lrow;
  int cb0 = nBase + wn + lrow;
  float bv[4];
#pragma unroll
  for (int f = 0; f < 4; ++f) bv[f] = bias[cb0 + 16 * f];

#pragma unroll
  for (int fm = 0; fm < 4; ++fm) {
    int rbase = mBase + wm + fm * 16 + (lane >> 4) * 4;
    float4 mv4 = *(const float4*)(mask + rbase);  // rows rbase..rbase+3
#pragma unroll
    for (int r = 0; r < 4; ++r) {
      int rr = rbase + r;
      float mval = (r == 0) ? mv4.x : (r == 1) ? mv4.y : (r == 2) ? mv4.z : mv4.w;
      if (mval != 0.0f) {
        float s = mval * 1.4426950408889634f;
        float b2[4];
#pragma unroll
        for (int f = 0; f < 4; ++f) b2[f] = fmaf(bv[f], s, -5.0f);
#pragma unroll
        for (int f = 0; f < 4; ++f) {
          float fe = fast_exp2(fmaf(acc[fm][f][r], s, b2[f]));
          int pk = __builtin_amdgcn_cvt_pk_fp8_f32(fe, fe, 0, false);
          ep0[fm * (16 * 144) + r * 144 + f * 16] = (char)pk;
        }
      } else {
        bool t0 = ((rr & 511) == 0);
#pragma unroll
        for (int f = 0; f < 4; ++f) {
          int c = cb0 + 16 * f;
          int ii = c / 80, jj = c - ii * 80;
          float fe = t0 ? ((jj < K_) ? 0.03125f : 0.f)
                        : ((ii == jj) ? 0.03125f : 0.f);  // scaled identity
          int pk = __builtin_amdgcn_cvt_pk_fp8_f32(fe, fe, 0, false);
          ep0[fm * (16 * 144) + r * 144 + f * 16] = (char)pk;
        }
      }
    }
  }
  __syncthreads();

  // ---- phase 2: stream LDS -> F / p0buf with 16B vector stores ----
#pragma unroll
  for (int m2 = 0; m2 < 4; ++m2) {
    int idx = tid + 256 * m2;          // 0..1023
    int row = idx >> 3, ch = idx & 7;  // tile row, 16B chunk
    uint4 dv = *(const uint4*)(Ep + row * 144 + ch * 16);
    int rr = mBase + row;
    int trow = rr & 511, b = rr >> 9;
    int c0 = nBase + ch * 16;
    if (trow != 0) {
      if (c0 < FMB)
        *(uint4*)(F + (size_t)(b * 511 + trow - 1) * FMB + c0) = dv;
    } else {
      if (c0 >= 5120 && c0 < FMB)      // t=0: keep only row 64 (p0)
        *(uint4*)(p0buf + b * FROW + (c0 - 5120)) = dv;
    }
  }
}

// ---------------- chain0: fp8 transposed-chain chunk products --------------
// 32 chunks/batch x ~16 mats: P <- P * (M_t)^T descending; G = straight fp8
// copy (async), A-init = (M_last)^T.  Output chunkOut bf16.
__global__ __launch_bounds__(256, 4) void chain0_kernel(
    const char* __restrict__ src, __hip_bfloat16* __restrict__ outM,
    int* __restrict__ scOut, const char* __restrict__ zsrc) {
  __shared__ __align__(16) char lds[3 * CB0];  // A | G0 | G1 (36 KiB)
  __shared__ float red[4];
  char* Als = lds;

  int tid = threadIdx.x, wid = tid >> 6, lane = tid & 63;
  int wr = wid >> 1, wc = wid & 1;
  int b = blockIdx.y, cx = blockIdx.x;

  long matLast = (long)b * 511 + 16 * cx + 14;   // m of t = 16cx+15
  int nb = (cx == 0) ? 14 : 15;
  int outIdx = b * 32 + cx;
  bool trOut = (cx & 7) != 7;
  int Kacc = 0;

  // async window source offsets: 9 windows (wids 0..2, 3 each)
  int soff[3];
#pragma unroll
  for (int k = 0; k < 3; ++k) {
    int W = wid * 3 + k;
    int row = W * 8 + (lane >> 3);
    int a2 = (lane & 7) ^ (row & 7);
    soff[k] = (a2 < 5 && row < K_) ? (row * FROW + a2 * 16) : -1;
  }

#define STAGE0(ldsbase, matbyte)                                        \
  do {                                                                  \
    if (wid < 3) {                                                      \
      _Pragma("unroll")                                                 \
      for (int k_ = 0; k_ < 3; ++k_) {                                  \
        int W_ = wid * 3 + k_;                                          \
        int off_ = soff[k_];                                            \
        const char* gp_ = (off_ >= 0) ? ((matbyte) + off_) : zsrc;      \
        async_ld16(gp_, (ldsbase) + W_ * 1024 + lane * 16);             \
      }                                                                 \
    }                                                                   \
  } while (0)

  // zero-init all buffers
  {
    uint4 zz = {0u, 0u, 0u, 0u};
    for (int z = tid; z < 3 * CB0 / 16; z += 256) ((uint4*)lds)[z] = zz;
  }
  __syncthreads();

  // A-init: transposed byte scatter of M_last (pads in F are zero already)
  {
    const uint4* s4 = (const uint4*)(src + (size_t)matLast * FMB);
#pragma unroll
    for (int m = 0; m < 2; ++m) {
      int u = tid + 256 * m;
      if (u < 325) {
        uint4 v = s4[u];
        int i = u / 5, j0 = (u % 5) * 16;
        const unsigned char* pv = (const unsigned char*)&v;
#pragma unroll
        for (int d = 0; d < 16; ++d)
          Als[swz8(j0 + d, i)] = pv[d];
      }
    }
  }
  STAGE0(lds + CB0, src + (size_t)(matLast - 1) * FMB);
  __syncthreads();  // full drain: A + G0 ready

  for (int s = 0; s < nb; ++s) {
    int g = s & 1;
    char* Gcur = lds + (1 + g) * CB0;
    char* Gnxt = lds + (1 + (g ^ 1)) * CB0;
    if (s + 1 < nb)
      STAGE0(Gnxt, src + (size_t)(matLast - 2 - s) * FMB);

    f32x4 acc[3][3];
#pragma unroll
    for (int r = 0; r < 3; ++r)
#pragma unroll
      for (int c = 0; c < 3; ++c) acc[r][c] = (f32x4){0.f, 0.f, 0.f, 0.f};
    __builtin_amdgcn_s_setprio(1);
#pragma unroll
    for (int kk = 0; kk < 96; kk += 32) {
      int cb = kk + (lane >> 4) * 8;
      i64 af[3], bg[3];
#pragma unroll
      for (int r = 0; r < 3; ++r)
        af[r] = *(const i64*)(Als + swz8((3 * wr + r) * 16 + (lane & 15), cb));
#pragma unroll
      for (int c = 0; c < 3; ++c)
        bg[c] = *(const i64*)(Gcur + swz8((3 * wc + c) * 16 + (lane & 15), cb));
#pragma unroll
      for (int r = 0; r < 3; ++r)
#pragma unroll
        for (int c = 0; c < 3; ++c)
          acc[r][c] = __builtin_amdgcn_mfma_f32_16x16x32_fp8_fp8(
              af[r], bg[c], acc[r][c], 0, 0, 0);
    }
    __builtin_amdgcn_s_setprio(0);

    // block max -> power-of-2 renorm
    float mx = 0.f;
#pragma unroll
    for (int r = 0; r < 3; ++r)
#pragma unroll
      for (int c = 0; c < 3; ++c)
#pragma unroll
        for (int q = 0; q < 4; ++q) mx = fmaxf(mx, acc[r][c][q]);
#pragma unroll
    for (int o = 32; o; o >>= 1) mx = fmaxf(mx, __shfl_xor(mx, o));
    if (lane == 0) red[wid] = mx;

    // B1: raw barrier, LDS-drain only — async loads stay in flight
    __builtin_amdgcn_sched_barrier(0);
    asm volatile("s_waitcnt lgkmcnt(0)" ::: "memory");
    __builtin_amdgcn_s_barrier();
    __builtin_amdgcn_sched_barrier(0);

    mx = fmaxf(fmaxf(red[0], red[1]), fmaxf(red[2], red[3]));
    int kx; frexpf(mx, &kx);
    Kacc += kx;
    float sc = ldexpf(1.0f, -kx);
    bool last = (s == nb - 1);

#pragma unroll
    for (int r = 0; r < 3; ++r) {
      int R0 = (3 * wr + r) * 16 + (lane >> 4) * 4;
#pragma unroll
      for (int c = 0; c < 3; ++c) {
        int C0 = (3 * wc + c) * 16 + (lane & 15);
#pragma unroll
        for (int q = 0; q < 4; ++q) {
          float val = acc[r][c][q] * sc;
          if (!last) {
            int pk = __builtin_amdgcn_cvt_pk_fp8_f32(val, val, 0, false);
            Als[swz8(R0 + q, C0)] = (char)pk;
          } else {
            __hip_bfloat16 h = __float2bfloat16(val);
            __hip_bfloat16* ob = outM + (size_t)outIdx * MELEM;
            int R = R0 + q;
            if (trOut) {
              if (C0 < K_ && R < MROW) ob[C0 * MROW + R] = h;
            } else {
              if (R < K_ && C0 < MROW) ob[(size_t)R * MROW + C0] = h;
            }
          }
        }
      }
    }
    __syncthreads();  // B2: full drain — writeback + staged G visible
  }
  if (tid == 0) scOut[outIdx] = Kacc;
#undef STAGE0
}

// ---------------- chain1: bf16 combine of 8 chunk matrices -----------------
__global__ __launch_bounds__(256, 2) void chain1_kernel(
    const __hip_bfloat16* __restrict__ src, const int* __restrict__ scIn,
    __hip_bfloat16* __restrict__ outM, int* __restrict__ scOut,
    const char* __restrict__ zsrc) {
  __shared__ __align__(16) __hip_bfloat16 lds[3 * LMAT2];  // A | G0 | G1
  __shared__ float red[4];
  __hip_bfloat16* Als = lds;

  int tid = threadIdx.x, wid = tid >> 6, lane = tid & 63;
  int wr = wid >> 1, wc = wid & 1;
  int b = blockIdx.y, cx = blockIdx.x;

  int i0 = b * 32 + 8 * cx;
  long matLast = i0 + 7;
  int nb = 7;
  int outIdx = b * 4 + cx;
  int Kacc = 0;
#pragma unroll
  for (int q = 0; q < 8; ++q) Kacc += scIn[i0 + q];

  int soff[5];
#pragma unroll
  for (int k = 0; k < 5; ++k) {
    int W = (k < 4) ? (wid * 4 + k) : 16;
    int a = 64 * W + lane;
    int row = a >> 4, ap = a & 15;
    int ch = (ap ^ row) & 15;
    soff[k] = (ch < 9 && row < K_) ? (row * 144 + ch * 16) : -1;
  }

#define STAGE1(ldsbyte, matbyte)                                        \
  do {                                                                  \
    _Pragma("unroll")                                                   \
    for (int k_ = 0; k_ < 5; ++k_) {                                    \
      if (k_ < 4 || wid == 0) {                                         \
        int W_ = (k_ < 4) ? (wid * 4 + k_) : 16;                        \
        int off_ = soff[k_];                                            \
        const char* gp_ = (off_ >= 0) ? ((matbyte) + off_) : zsrc;      \
        async_ld16(gp_, (ldsbyte) + W_ * 1024 + lane * 16);             \
      }                                                                 \
    }                                                                   \
  } while (0)

  {
    uint4 zz = {0u, 0u, 0u, 0u};
    for (int z = tid; z < 3 * GBYTE / 16; z += 256) ((uint4*)lds)[z] = zz;
  }
  __syncthreads();

  STAGE1((char*)Als, (const char*)src + (size_t)matLast * MBYTE);
  STAGE1((char*)lds + GBYTE, (const char*)src + (size_t)(matLast - 1) * MBYTE);
  __syncthreads();

  for (int s = 0; s < nb; ++s) {
    int g = s & 1;
    char* Gcur = (char*)lds + (1 + g) * GBYTE;
    char* Gnxt = (char*)lds + (1 + (g ^ 1)) * GBYTE;
    if (s + 1 < nb)
      STAGE1(Gnxt, (const char*)src + (size_t)(matLast - 2 - s) * MBYTE);
    const __hip_bfloat16* Gb = (const __hip_bfloat16*)Gcur;

    f32x4 acc[3][3];
#pragma unroll
    for (int r = 0; r < 3; ++r)
#pragma unroll
      for (int c = 0; c < 3; ++c) acc[r][c] = (f32x4){0.f, 0.f, 0.f, 0.f};
    __builtin_amdgcn_s_setprio(1);
#pragma unroll
    for (int kk = 0; kk < 96; kk += 32) {
      int cb = kk + (lane >> 4) * 8;
      bf16x8 af[3], bg[3];
#pragma unroll
      for (int r = 0; r < 3; ++r)
        af[r] = *(const bf16x8*)(Als + swzc((3 * wr + r) * 16 + (lane & 15), cb));
#pragma unroll
      for (int c = 0; c < 3; ++c)
        bg[c] = *(const bf16x8*)(Gb + swzc((3 * wc + c) * 16 + (lane & 15), cb));
#pragma unroll
      for (int r = 0; r < 3; ++r)
#pragma unroll
        for (int c = 0; c < 3; ++c)
          acc[r][c] = __builtin_amdgcn_mfma_f32_16x16x32_bf16(af[r], bg[c], acc[r][c], 0, 0, 0);
    }
    __builtin_amdgcn_s_setprio(0);

    float mx = 0.f;
#pragma unroll
    for (int r = 0; r < 3; ++r)
#pragma unroll
      for (int c = 0; c < 3; ++c)
#pragma unroll
        for (int q = 0; q < 4; ++q) mx = fmaxf(mx, acc[r][c][q]);
#pragma unroll
    for (int o = 32; o; o >>= 1) mx = fmaxf(mx, __shfl_xor(mx, o));
    if (lane == 0) red[wid] = mx;

    __builtin_amdgcn_sched_barrier(0);
    asm volatile("s_waitcnt lgkmcnt(0)" ::: "memory");
    __builtin_amdgcn_s_barrier();
    __builtin_amdgcn_sched_barrier(0);

    mx = fmaxf(fmaxf(red[0], red[1]), fmaxf(red[2], red[3]));
    int kx; frexpf(mx, &kx);
    Kacc += kx;
    float sc = ldexpf(1.0f, -kx);
    bool last = (s == nb - 1);

#pragma unroll
    for (int r = 0; r < 3; ++r) {
      int R0 = (3 * wr + r) * 16 + (lane >> 4) * 4;
#pragma unroll
      for (int c = 0; c < 3; ++c) {
        int C0 = (3 * wc + c) * 16 + (lane & 15);
#pragma unroll
        for (int q = 0; q < 4; ++q) {
          __hip_bfloat16 h = __float2bfloat16(acc[r][c][q] * sc);
          if (!last) {
            Als[swzc(R0 + q, C0)] = h;
          } else {
            __hip_bfloat16* ob = outM + (size_t)outIdx * MELEM;
            int R = R0 + q;
            if (R < K_ && C0 < MROW) ob[(size_t)R * MROW + C0] = h;
          }
        }
      }
    }
    __syncthreads();
  }
  if (tid == 0) scOut[outIdx] = Kacc;
#undef STAGE1
}

// ---------------- final: p0 (fp8, 2^-5-scaled) through 4 bf16 matrices -----
__global__ __launch_bounds__(256) void final_kernel(
    const char* __restrict__ p0buf, const __hip_bfloat16* __restrict__ levA,
    const int* __restrict__ sc2, const float* __restrict__ tgtE,
    float* __restrict__ out) {
  __shared__ float v[2][80];
  __shared__ float rs[8];
  int b = blockIdx.x, tid = threadIdx.x;
  if (tid < K_) {
    int byte = (int)(unsigned char)p0buf[b * FROW + tid];
    v[0][tid] = __builtin_amdgcn_cvt_f32_fp8(byte, 0);
  }
  __syncthreads();
  int cur = 0;
  for (int m = 0; m < 4; ++m) {
    const __hip_bfloat16* T = levA + (size_t)(b * 4 + m) * MELEM;  // Y^T row-major
    if (tid < K_) {
      float s = 0.f;
      for (int i = 0; i < K_; ++i)
        s += v[cur][i] * __bfloat162float(T[tid * MROW + i]);
      v[1 - cur][tid] = s;
    }
    cur ^= 1;
    __syncthreads();
  }
  float tv = tgtE[b * 512 + tid] + tgtE[b * 512 + 256 + tid];
#pragma unroll
  for (int o = 32; o; o >>= 1) tv += __shfl_xor(tv, o);
  if ((tid & 63) == 0) rs[4 + (tid >> 6)] = tv;
  if (tid < 64) {
    float zz = v[cur][tid] + ((tid == 0) ? v[cur][64] : 0.f);
#pragma unroll
    for (int o = 32; o; o >>= 1) zz += __shfl_xor(zz, o);
    if (tid == 0) rs[0] = zz;
  }
  __syncthreads();
  if (tid == 0) {
    float tg = rs[4] + rs[5] + rs[6] + rs[7];
    int S = sc2[4 * b] + sc2[4 * b + 1] + sc2[4 * b + 2] + sc2[4 * b + 3];
    // +2560 = 5 * (511 chain matrices + p0): every stored fp8 matrix carries
    // the global 2^-5 pre-scale, which the frexp renorm does NOT absorb.
    out[b] = logf(rs[0]) + 0.6931471805599453f * (float)(S + 2560) - tg;
  }
}

// ---------------- launch ----------------
extern "C" void kernel_launch(void* const* d_in, const int* in_sizes, int n_in,
                              void* d_out, int out_size, void* d_ws, size_t ws_size,
                              hipStream_t stream) {
  const float* x      = (const float*)d_in[0];
  const float* Ws     = (const float*)d_in[1];
  const float* bs     = (const float*)d_in[2];
  const float* Wt     = (const float*)d_in[3];
  const float* bt     = (const float*)d_in[4];
  const int*   target = (const int*)d_in[5];
  const float* mask   = (const float*)d_in[6];
  float* out = (float*)d_out;

  char* ws = (char*)d_ws;
  __hip_bfloat16* xbf   = (__hip_bfloat16*)(ws);                //  8,388,608 (dead after gemm)
  __hip_bfloat16* wbf   = (__hip_bfloat16*)(ws + 8388608);      //  2,686,976 (dead after gemm)
  float*          bias  = (float*)(ws + 11075584);              //     20,992
  char*           zreg  = (ws + 11096576);                      //        256 (zeros)
  float*          tgtE  = (float*)(ws + 11096832);              //     65,536
  char*           p0buf = (ws + 11162368);                      //      2,560 (fp8)
  char*           F     = (ws + 11164928);                      // 16352*5200 = 85,030,400 -> ends 96,195,328
  // reuse of dead regions (chain era; all < 11,075,584):
  __hip_bfloat16* chunkOut = (__hip_bfloat16*)(ws);             // 1024*9360 = 9,584,640
  int*            sc1      = (int*)(ws + 9584640);              //      4,096
  __hip_bfloat16* levA     = (__hip_bfloat16*)(ws + 9588736);   // 128*9360 = 1,198,080
  int*            sc2      = (int*)(ws + 10786816);             //        512

  hipLaunchKernelGGL(prep_kernel, dim3(NP3 + M_ / 4), dim3(256), 0, stream,
                     x, Ws, bs, Wt, bt, target, mask,
                     wbf, bias, (uint*)zreg, xbf, tgtE);
  hipLaunchKernelGGL(gemm_exp_kernel, dim3(M_ / 128, NP3 / 128), dim3(256), 0, stream,
                     xbf, wbf, bias, mask, F, p0buf);
  hipLaunchKernelGGL(chain0_kernel, dim3(32, 32), dim3(256), 0, stream,
                     F, chunkOut, sc1, zreg);
  hipLaunchKernelGGL(chain1_kernel, dim3(4, 32), dim3(256), 0, stream,
                     chunkOut, sc1, levA, sc2, zreg);
  hipLaunchKernelGGL(final_kernel, dim3(B_), dim3(256), 0, stream,
                     p0buf, levA, sc2, tgtE, out);
}

// Round 22
// 151.250 us; speedup vs baseline: 1.1027x; 1.1027x over previous
//
#include <hip/hip_runtime.h>
#include <hip/hip_bf16.h>
#include <stdint.h>

#define B_  32
#define L_  512
#define D_  256
#define K_  65
#define FROW 80        // F-matrix row stride in BYTES (fp8), 16B-divisible
#define FMB  5200      // bytes per fp8 F matrix (65*80)
#define NP3  5248      // padded GEMM N: 41*128 (n = 80*i + j)
#define M_   16384     // B_*L_
#define MROW 72        // chunkOut row stride (bf16 elems)
#define MELEM 4680     // 65*72 elems per bf16 matrix
#define MBYTE 9360     // bytes per bf16 matrix
#define CB0  12288     // chain0 LDS bytes per buffer (96*128)
#define LMAT2 12288    // chain1 LDS elems per buffer (96*128 bf16)
#define GBYTE 24576    // chain1 LDS bytes per buffer

typedef __attribute__((ext_vector_type(8))) short bf16x8;
typedef __attribute__((ext_vector_type(4))) float f32x4;
typedef long long i64;

typedef unsigned int u32g __attribute__((address_space(1)));
typedef unsigned int u32l __attribute__((address_space(3)));

__device__ __forceinline__ void async_ld16(const void* g, void* l) {
  __builtin_amdgcn_global_load_lds((const u32g*)g, (u32l*)l, 16, 0, 0);
}

// bare v_exp_f32 (2^x): single trans-pipe instruction, no OCML range wrapper.
// Args here are bounded (|x| < ~70), denormal flush is fine (fp8 target).
__device__ __forceinline__ float fast_exp2(float x) {
  float r;
  asm("v_exp_f32 %0, %1" : "=v"(r) : "v"(x));
  return r;
}

// fp8 chain LDS [96 rows][128 B]: 16B-atom XOR swizzle; c = byte col 0..95
__device__ __forceinline__ int swz8(int row, int c) {
  return row * 128 + (c & 15) + ((((c >> 4) ^ row) & 7) << 4);
}
// bf16 chain LDS [96][128 elems]
__device__ __forceinline__ int swzc(int row, int col) {
  return row * 128 + (col & 7) + ((((col >> 3) ^ row) & 15) << 3);
}
// gemm LDS [128][64 elems]
__device__ __forceinline__ int swzg(int row, int col) {
  return row * 64 + ((col & 7) | ((((col >> 3) ^ row) & 7) << 3));
}

// ---------------- prep (fused): W-pack + x-pack + exact tgt score ----------
__global__ __launch_bounds__(256) void prep_kernel(
    const float* __restrict__ x, const float* __restrict__ Ws,
    const float* __restrict__ bs, const float* __restrict__ Wt,
    const float* __restrict__ bt, const int* __restrict__ target,
    const float* __restrict__ mask,
    __hip_bfloat16* __restrict__ wbf, float* __restrict__ bias,
    uint* __restrict__ zreg,
    __hip_bfloat16* __restrict__ xbf, float* __restrict__ tgtE) {
  if (blockIdx.x < NP3) {
    // ---- W'[n=80i+j] = Wt[i*65+j] + Ws[j]; pad bias = -1e30 ----
    int n = blockIdx.x, d = threadIdx.x;
    int i = n / 80, j = n - i * 80;
    bool valid = (j < K_) && (i < K_);
    float v = 0.f;
    if (valid) v = Wt[(size_t)(i * 65 + j) * D_ + d] + Ws[(size_t)j * D_ + d];
    wbf[(size_t)n * D_ + d] = __float2bfloat16(v);
    if (d == 0) bias[n] = valid ? (bt[i * 65 + j] + bs[j]) : -1e30f;
    if (n == 0 && d < 64) zreg[d] = 0u;
  } else {
    // ---- x -> bf16 + fused tgt-path score (one wave per (b,t) row) ----
    int wid = threadIdx.x >> 6, lane = threadIdx.x & 63;
    int row = (blockIdx.x - NP3) * 4 + wid;  // 0..M_-1
    int t = row & 511;
    float4 xx = ((const float4*)x)[row * 64 + lane];
    __hip_bfloat16 o[4] = {__float2bfloat16(xx.x), __float2bfloat16(xx.y),
                           __float2bfloat16(xx.z), __float2bfloat16(xx.w)};
    *(uint2*)(xbf + (size_t)row * D_ + lane * 4) = *(const uint2*)o;

    int y = target[row];
    int prev = (t == 0) ? (K_ - 1) : target[row - 1];
    int p = prev * 65 + y;
    float4 aa = ((const float4*)(Wt + (size_t)p * D_))[lane];
    float4 cc = ((const float4*)(Ws + (size_t)y * D_))[lane];
    float acc = xx.x * (aa.x + cc.x) + xx.y * (aa.y + cc.y) +
                xx.z * (aa.z + cc.z) + xx.w * (aa.w + cc.w);
#pragma unroll
    for (int o2 = 32; o2; o2 >>= 1) acc += __shfl_xor(acc, o2);
    if (lane == 0) tgtE[row] = (acc + bt[p] + bs[y]) * mask[row];
  }
}

// ---------------- GEMM: F = fp8( 2^-5 * exp((A*B^T + bias) * mask) ) -------
// F fp8 matrices t=1..511 at m = b*511+(t-1), 80-B rows; t=0 row64 -> p0buf
__global__ __launch_bounds__(256) void gemm_exp_kernel(
    const __hip_bfloat16* __restrict__ A, const __hip_bfloat16* __restrict__ Bm,
    const float* __restrict__ bias, const float* __restrict__ mask,
    char* __restrict__ F, char* __restrict__ p0buf) {
  __shared__ __align__(16) char shm[32768];  // K-loop: As|Bs ; epilogue: Ep[128][144]
  __hip_bfloat16* As = (__hip_bfloat16*)shm;
  __hip_bfloat16* Bs = (__hip_bfloat16*)(shm + 16384);
  int tid = threadIdx.x;
  int mBase = blockIdx.x * 128;
  int nBase = blockIdx.y * 128;
  int wid = tid >> 6, lane = tid & 63;
  int wm = (wid >> 1) * 64, wn = (wid & 1) * 64;
  int lrow = lane & 15, lk = (lane >> 4) * 8;

  f32x4 acc[4][4];
#pragma unroll
  for (int a = 0; a < 4; ++a)
#pragma unroll
    for (int c = 0; c < 4; ++c) acc[a][c] = (f32x4){0.f, 0.f, 0.f, 0.f};

  int gsrc = (((tid & 7) ^ ((tid >> 3) & 7))) * 8;
  const __hip_bfloat16* aSrc = A + (size_t)(mBase + (tid >> 3)) * D_ + gsrc;
  const __hip_bfloat16* bSrc = Bm + (size_t)(nBase + (tid >> 3)) * D_ + gsrc;
  char* aDst = shm + tid * 16;
  char* bDst = shm + 16384 + tid * 16;

  for (int kt = 0; kt < D_; kt += 64) {
#pragma unroll
    for (int i = 0; i < 4; ++i) {
      async_ld16(aSrc + (size_t)i * 32 * D_ + kt, aDst + i * 4096);
      async_ld16(bSrc + (size_t)i * 32 * D_ + kt, bDst + i * 4096);
    }
    __syncthreads();
#pragma unroll
    for (int kk = 0; kk < 64; kk += 32) {
      bf16x8 af[4], bfr[4];
#pragma unroll
      for (int f = 0; f < 4; ++f) {
        af[f]  = *(const bf16x8*)(As + swzg(wm + f * 16 + lrow, kk + lk));
        bfr[f] = *(const bf16x8*)(Bs + swzg(wn + f * 16 + lrow, kk + lk));
      }
      __builtin_amdgcn_s_setprio(1);
#pragma unroll
      for (int fm = 0; fm < 4; ++fm)
#pragma unroll
        for (int fn = 0; fn < 4; ++fn)
          acc[fm][fn] = __builtin_amdgcn_mfma_f32_16x16x32_bf16(
              af[fm], bfr[fn], acc[fm][fn], 0, 0, 0);
      __builtin_amdgcn_s_setprio(0);
    }
    __syncthreads();
  }

  // ---- phase 1: fp8 epilogue -> LDS Ep[128][144] ----
  char* Ep = shm;
  char* ep0 = Ep + (wm + (lane >> 4) * 4) * 144 + wn + lrow;
  int cb0 = nBase + wn + lrow;
  float bv[4];
#pragma unroll
  for (int f = 0; f < 4; ++f) bv[f] = bias[cb0 + 16 * f];

#pragma unroll
  for (int fm = 0; fm < 4; ++fm) {
    int rbase = mBase + wm + fm * 16 + (lane >> 4) * 4;
    float4 mv4 = *(const float4*)(mask + rbase);  // rows rbase..rbase+3
#pragma unroll
    for (int r = 0; r < 4; ++r) {
      int rr = rbase + r;
      float mval = (r == 0) ? mv4.x : (r == 1) ? mv4.y : (r == 2) ? mv4.z : mv4.w;
      if (mval != 0.0f) {
        float s = mval * 1.4426950408889634f;
        float b2[4];
#pragma unroll
        for (int f = 0; f < 4; ++f) b2[f] = fmaf(bv[f], s, -5.0f);
#pragma unroll
        for (int f = 0; f < 4; ++f) {
          float fe = fast_exp2(fmaf(acc[fm][f][r], s, b2[f]));
          int pk = __builtin_amdgcn_cvt_pk_fp8_f32(fe, fe, 0, false);
          ep0[fm * (16 * 144) + r * 144 + f * 16] = (char)pk;
        }
      } else {
        bool t0 = ((rr & 511) == 0);
#pragma unroll
        for (int f = 0; f < 4; ++f) {
          int c = cb0 + 16 * f;
          int ii = c / 80, jj = c - ii * 80;
          float fe = t0 ? ((jj < K_) ? 0.03125f : 0.f)
                        : ((ii == jj) ? 0.03125f : 0.f);  // scaled identity
          int pk = __builtin_amdgcn_cvt_pk_fp8_f32(fe, fe, 0, false);
          ep0[fm * (16 * 144) + r * 144 + f * 16] = (char)pk;
        }
      }
    }
  }
  __syncthreads();

  // ---- phase 2: stream LDS -> F / p0buf with 16B vector stores ----
#pragma unroll
  for (int m2 = 0; m2 < 4; ++m2) {
    int idx = tid + 256 * m2;          // 0..1023
    int row = idx >> 3, ch = idx & 7;  // tile row, 16B chunk
    uint4 dv = *(const uint4*)(Ep + row * 144 + ch * 16);
    int rr = mBase + row;
    int trow = rr & 511, b = rr >> 9;
    int c0 = nBase + ch * 16;
    if (trow != 0) {
      if (c0 < FMB)
        *(uint4*)(F + (size_t)(b * 511 + trow - 1) * FMB + c0) = dv;
    } else {
      if (c0 >= 5120 && c0 < FMB)      // t=0: keep only row 64 (p0)
        *(uint4*)(p0buf + b * FROW + (c0 - 5120)) = dv;
    }
  }
}

// ---------------- chain0: fp8 transposed-chain chunk products --------------
// 32 chunks/batch x ~16 mats: P <- P * (M_t)^T descending; G = straight fp8
// copy (async), A-init = (M_last)^T.  Output chunkOut bf16.
__global__ __launch_bounds__(256, 4) void chain0_kernel(
    const char* __restrict__ src, __hip_bfloat16* __restrict__ outM,
    int* __restrict__ scOut, const char* __restrict__ zsrc) {
  __shared__ __align__(16) char lds[3 * CB0];  // A | G0 | G1 (36 KiB)
  __shared__ float red[4];
  char* Als = lds;

  int tid = threadIdx.x, wid = tid >> 6, lane = tid & 63;
  int wr = wid >> 1, wc = wid & 1;
  int b = blockIdx.y, cx = blockIdx.x;

  long matLast = (long)b * 511 + 16 * cx + 14;   // m of t = 16cx+15
  int nb = (cx == 0) ? 14 : 15;
  int outIdx = b * 32 + cx;
  bool trOut = (cx & 7) != 7;
  int Kacc = 0;

  // async window source offsets: 9 windows (wids 0..2, 3 each)
  int soff[3];
#pragma unroll
  for (int k = 0; k < 3; ++k) {
    int W = wid * 3 + k;
    int row = W * 8 + (lane >> 3);
    int a2 = (lane & 7) ^ (row & 7);
    soff[k] = (a2 < 5 && row < K_) ? (row * FROW + a2 * 16) : -1;
  }

#define STAGE0(ldsbase, matbyte)                                        \
  do {                                                                  \
    if (wid < 3) {                                                      \
      _Pragma("unroll")                                                 \
      for (int k_ = 0; k_ < 3; ++k_) {                                  \
        int W_ = wid * 3 + k_;                                          \
        int off_ = soff[k_];                                            \
        const char* gp_ = (off_ >= 0) ? ((matbyte) + off_) : zsrc;      \
        async_ld16(gp_, (ldsbase) + W_ * 1024 + lane * 16);             \
      }                                                                 \
    }                                                                   \
  } while (0)

  // zero-init all buffers
  {
    uint4 zz = {0u, 0u, 0u, 0u};
    for (int z = tid; z < 3 * CB0 / 16; z += 256) ((uint4*)lds)[z] = zz;
  }
  __syncthreads();

  // A-init: transposed byte scatter of M_last (pads in F are zero already)
  {
    const uint4* s4 = (const uint4*)(src + (size_t)matLast * FMB);
#pragma unroll
    for (int m = 0; m < 2; ++m) {
      int u = tid + 256 * m;
      if (u < 325) {
        uint4 v = s4[u];
        int i = u / 5, j0 = (u % 5) * 16;
        const unsigned char* pv = (const unsigned char*)&v;
#pragma unroll
        for (int d = 0; d < 16; ++d)
          Als[swz8(j0 + d, i)] = pv[d];
      }
    }
  }
  STAGE0(lds + CB0, src + (size_t)(matLast - 1) * FMB);
  __syncthreads();  // full drain: A + G0 ready

  for (int s = 0; s < nb; ++s) {
    int g = s & 1;
    char* Gcur = lds + (1 + g) * CB0;
    char* Gnxt = lds + (1 + (g ^ 1)) * CB0;
    if (s + 1 < nb)
      STAGE0(Gnxt, src + (size_t)(matLast - 2 - s) * FMB);

    f32x4 acc[3][3];
#pragma unroll
    for (int r = 0; r < 3; ++r)
#pragma unroll
      for (int c = 0; c < 3; ++c) acc[r][c] = (f32x4){0.f, 0.f, 0.f, 0.f};
    __builtin_amdgcn_s_setprio(1);
#pragma unroll
    for (int kk = 0; kk < 96; kk += 32) {
      int cb = kk + (lane >> 4) * 8;
      i64 af[3], bg[3];
#pragma unroll
      for (int r = 0; r < 3; ++r)
        af[r] = *(const i64*)(Als + swz8((3 * wr + r) * 16 + (lane & 15), cb));
#pragma unroll
      for (int c = 0; c < 3; ++c)
        bg[c] = *(const i64*)(Gcur + swz8((3 * wc + c) * 16 + (lane & 15), cb));
#pragma unroll
      for (int r = 0; r < 3; ++r)
#pragma unroll
        for (int c = 0; c < 3; ++c)
          acc[r][c] = __builtin_amdgcn_mfma_f32_16x16x32_fp8_fp8(
              af[r], bg[c], acc[r][c], 0, 0, 0);
    }
    __builtin_amdgcn_s_setprio(0);

    // block max -> power-of-2 renorm
    float mx = 0.f;
#pragma unroll
    for (int r = 0; r < 3; ++r)
#pragma unroll
      for (int c = 0; c < 3; ++c)
#pragma unroll
        for (int q = 0; q < 4; ++q) mx = fmaxf(mx, acc[r][c][q]);
#pragma unroll
    for (int o = 32; o; o >>= 1) mx = fmaxf(mx, __shfl_xor(mx, o));
    if (lane == 0) red[wid] = mx;

    // B1: raw barrier, LDS-drain only — async loads stay in flight
    __builtin_amdgcn_sched_barrier(0);
    asm volatile("s_waitcnt lgkmcnt(0)" ::: "memory");
    __builtin_amdgcn_s_barrier();
    __builtin_amdgcn_sched_barrier(0);

    mx = fmaxf(fmaxf(red[0], red[1]), fmaxf(red[2], red[3]));
    int kx; frexpf(mx, &kx);
    Kacc += kx;
    float sc = ldexpf(1.0f, -kx);
    bool last = (s == nb - 1);

#pragma unroll
    for (int r = 0; r < 3; ++r) {
      int R0 = (3 * wr + r) * 16 + (lane >> 4) * 4;
#pragma unroll
      for (int c = 0; c < 3; ++c) {
        int C0 = (3 * wc + c) * 16 + (lane & 15);
#pragma unroll
        for (int q = 0; q < 4; ++q) {
          float val = acc[r][c][q] * sc;
          if (!last) {
            int pk = __builtin_amdgcn_cvt_pk_fp8_f32(val, val, 0, false);
            Als[swz8(R0 + q, C0)] = (char)pk;
          } else {
            __hip_bfloat16 h = __float2bfloat16(val);
            __hip_bfloat16* ob = outM + (size_t)outIdx * MELEM;
            int R = R0 + q;
            if (trOut) {
              if (C0 < K_ && R < MROW) ob[C0 * MROW + R] = h;
            } else {
              if (R < K_ && C0 < MROW) ob[(size_t)R * MROW + C0] = h;
            }
          }
        }
      }
    }
    __syncthreads();  // B2: full drain — writeback + staged G visible
  }
  if (tid == 0) scOut[outIdx] = Kacc;
#undef STAGE0
}

// ---------------- chain1: bf16 combine of 8 chunk matrices -----------------
__global__ __launch_bounds__(256, 2) void chain1_kernel(
    const __hip_bfloat16* __restrict__ src, const int* __restrict__ scIn,
    __hip_bfloat16* __restrict__ outM, int* __restrict__ scOut,
    const char* __restrict__ zsrc) {
  __shared__ __align__(16) __hip_bfloat16 lds[3 * LMAT2];  // A | G0 | G1
  __shared__ float red[4];
  __hip_bfloat16* Als = lds;

  int tid = threadIdx.x, wid = tid >> 6, lane = tid & 63;
  int wr = wid >> 1, wc = wid & 1;
  int b = blockIdx.y, cx = blockIdx.x;

  int i0 = b * 32 + 8 * cx;
  long matLast = i0 + 7;
  int nb = 7;
  int outIdx = b * 4 + cx;
  int Kacc = 0;
#pragma unroll
  for (int q = 0; q < 8; ++q) Kacc += scIn[i0 + q];

  int soff[5];
#pragma unroll
  for (int k = 0; k < 5; ++k) {
    int W = (k < 4) ? (wid * 4 + k) : 16;
    int a = 64 * W + lane;
    int row = a >> 4, ap = a & 15;
    int ch = (ap ^ row) & 15;
    soff[k] = (ch < 9 && row < K_) ? (row * 144 + ch * 16) : -1;
  }

#define STAGE1(ldsbyte, matbyte)                                        \
  do {                                                                  \
    _Pragma("unroll")                                                   \
    for (int k_ = 0; k_ < 5; ++k_) {                                    \
      if (k_ < 4 || wid == 0) {                                         \
        int W_ = (k_ < 4) ? (wid * 4 + k_) : 16;                        \
        int off_ = soff[k_];                                            \
        const char* gp_ = (off_ >= 0) ? ((matbyte) + off_) : zsrc;      \
        async_ld16(gp_, (ldsbyte) + W_ * 1024 + lane * 16);             \
      }                                                                 \
    }                                                                   \
  } while (0)

  {
    uint4 zz = {0u, 0u, 0u, 0u};
    for (int z = tid; z < 3 * GBYTE / 16; z += 256) ((uint4*)lds)[z] = zz;
  }
  __syncthreads();

  STAGE1((char*)Als, (const char*)src + (size_t)matLast * MBYTE);
  STAGE1((char*)lds + GBYTE, (const char*)src + (size_t)(matLast - 1) * MBYTE);
  __syncthreads();

  for (int s = 0; s < nb; ++s) {
    int g = s & 1;
    char* Gcur = (char*)lds + (1 + g) * GBYTE;
    char* Gnxt = (char*)lds + (1 + (g ^ 1)) * GBYTE;
    if (s + 1 < nb)
      STAGE1(Gnxt, (const char*)src + (size_t)(matLast - 2 - s) * MBYTE);
    const __hip_bfloat16* Gb = (const __hip_bfloat16*)Gcur;

    f32x4 acc[3][3];
#pragma unroll
    for (int r = 0; r < 3; ++r)
#pragma unroll
      for (int c = 0; c < 3; ++c) acc[r][c] = (f32x4){0.f, 0.f, 0.f, 0.f};
    __builtin_amdgcn_s_setprio(1);
#pragma unroll
    for (int kk = 0; kk < 96; kk += 32) {
      int cb = kk + (lane >> 4) * 8;
      bf16x8 af[3], bg[3];
#pragma unroll
      for (int r = 0; r < 3; ++r)
        af[r] = *(const bf16x8*)(Als + swzc((3 * wr + r) * 16 + (lane & 15), cb));
#pragma unroll
      for (int c = 0; c < 3; ++c)
        bg[c] = *(const bf16x8*)(Gb + swzc((3 * wc + c) * 16 + (lane & 15), cb));
#pragma unroll
      for (int r = 0; r < 3; ++r)
#pragma unroll
        for (int c = 0; c < 3; ++c)
          acc[r][c] = __builtin_amdgcn_mfma_f32_16x16x32_bf16(af[r], bg[c], acc[r][c], 0, 0, 0);
    }
    __builtin_amdgcn_s_setprio(0);

    float mx = 0.f;
#pragma unroll
    for (int r = 0; r < 3; ++r)
#pragma unroll
      for (int c = 0; c < 3; ++c)
#pragma unroll
        for (int q = 0; q < 4; ++q) mx = fmaxf(mx, acc[r][c][q]);
#pragma unroll
    for (int o = 32; o; o >>= 1) mx = fmaxf(mx, __shfl_xor(mx, o));
    if (lane == 0) red[wid] = mx;

    __builtin_amdgcn_sched_barrier(0);
    asm volatile("s_waitcnt lgkmcnt(0)" ::: "memory");
    __builtin_amdgcn_s_barrier();
    __builtin_amdgcn_sched_barrier(0);

    mx = fmaxf(fmaxf(red[0], red[1]), fmaxf(red[2], red[3]));
    int kx; frexpf(mx, &kx);
    Kacc += kx;
    float sc = ldexpf(1.0f, -kx);
    bool last = (s == nb - 1);

#pragma unroll
    for (int r = 0; r < 3; ++r) {
      int R0 = (3 * wr + r) * 16 + (lane >> 4) * 4;
#pragma unroll
      for (int c = 0; c < 3; ++c) {
        int C0 = (3 * wc + c) * 16 + (lane & 15);
#pragma unroll
        for (int q = 0; q < 4; ++q) {
          __hip_bfloat16 h = __float2bfloat16(acc[r][c][q] * sc);
          if (!last) {
            Als[swzc(R0 + q, C0)] = h;
          } else {
            __hip_bfloat16* ob = outM + (size_t)outIdx * MELEM;
            int R = R0 + q;
            if (R < K_ && C0 < MROW) ob[(size_t)R * MROW + C0] = h;
          }
        }
      }
    }
    __syncthreads();
  }
  if (tid == 0) scOut[outIdx] = Kacc;
#undef STAGE1
}

// ---------------- final: p0 (fp8, 2^-5-scaled) through 4 bf16 matrices -----
__global__ __launch_bounds__(256) void final_kernel(
    const char* __restrict__ p0buf, const __hip_bfloat16* __restrict__ levA,
    const int* __restrict__ sc2, const float* __restrict__ tgtE,
    float* __restrict__ out) {
  __shared__ float v[2][80];
  __shared__ float rs[8];
  int b = blockIdx.x, tid = threadIdx.x;
  if (tid < K_) {
    int byte = (int)(unsigned char)p0buf[b * FROW + tid];
    v[0][tid] = __builtin_amdgcn_cvt_f32_fp8(byte, 0);
  }
  __syncthreads();
  int cur = 0;
  for (int m = 0; m < 4; ++m) {
    const __hip_bfloat16* T = levA + (size_t)(b * 4 + m) * MELEM;  // Y^T row-major
    if (tid < K_) {
      float s = 0.f;
      for (int i = 0; i < K_; ++i)
        s += v[cur][i] * __bfloat162float(T[tid * MROW + i]);
      v[1 - cur][tid] = s;
    }
    cur ^= 1;
    __syncthreads();
  }
  float tv = tgtE[b * 512 + tid] + tgtE[b * 512 + 256 + tid];
#pragma unroll
  for (int o = 32; o; o >>= 1) tv += __shfl_xor(tv, o);
  if ((tid & 63) == 0) rs[4 + (tid >> 6)] = tv;
  if (tid < 64) {
    float zz = v[cur][tid] + ((tid == 0) ? v[cur][64] : 0.f);
#pragma unroll
    for (int o = 32; o; o >>= 1) zz += __shfl_xor(zz, o);
    if (tid == 0) rs[0] = zz;
  }
  __syncthreads();
  if (tid == 0) {
    float tg = rs[4] + rs[5] + rs[6] + rs[7];
    int S = sc2[4 * b] + sc2[4 * b + 1] + sc2[4 * b + 2] + sc2[4 * b + 3];
    // +2560 = 5 * (511 chain matrices + p0): every stored fp8 matrix carries
    // the global 2^-5 pre-scale, which the frexp renorm does NOT absorb.
    out[b] = logf(rs[0]) + 0.6931471805599453f * (float)(S + 2560) - tg;
  }
}

// ---------------- launch ----------------
extern "C" void kernel_launch(void* const* d_in, const int* in_sizes, int n_in,
                              void* d_out, int out_size, void* d_ws, size_t ws_size,
                              hipStream_t stream) {
  const float* x      = (const float*)d_in[0];
  const float* Ws     = (const float*)d_in[1];
  const float* bs     = (const float*)d_in[2];
  const float* Wt     = (const float*)d_in[3];
  const float* bt     = (const float*)d_in[4];
  const int*   target = (const int*)d_in[5];
  const float* mask   = (const float*)d_in[6];
  float* out = (float*)d_out;

  char* ws = (char*)d_ws;
  __hip_bfloat16* xbf   = (__hip_bfloat16*)(ws);                //  8,388,608 (dead after gemm)
  __hip_bfloat16* wbf   = (__hip_bfloat16*)(ws + 8388608);      //  2,686,976 (dead after gemm)
  float*          bias  = (float*)(ws + 11075584);              //     20,992
  char*           zreg  = (ws + 11096576);                      //        256 (zeros)
  float*          tgtE  = (float*)(ws + 11096832);              //     65,536
  char*           p0buf = (ws + 11162368);                      //      2,560 (fp8)
  char*           F     = (ws + 11164928);                      // 16352*5200 = 85,030,400 -> ends 96,195,328
  // reuse of dead regions (chain era; all < 11,075,584):
  __hip_bfloat16* chunkOut = (__hip_bfloat16*)(ws);             // 1024*9360 = 9,584,640
  int*            sc1      = (int*)(ws + 9584640);              //      4,096
  __hip_bfloat16* levA     = (__hip_bfloat16*)(ws + 9588736);   // 128*9360 = 1,198,080
  int*            sc2      = (int*)(ws + 10786816);             //        512

  hipLaunchKernelGGL(prep_kernel, dim3(NP3 + M_ / 4), dim3(256), 0, stream,
                     x, Ws, bs, Wt, bt, target, mask,
                     wbf, bias, (uint*)zreg, xbf, tgtE);
  hipLaunchKernelGGL(gemm_exp_kernel, dim3(M_ / 128, NP3 / 128), dim3(256), 0, stream,
                     xbf, wbf, bias, mask, F, p0buf);
  hipLaunchKernelGGL(chain0_kernel, dim3(32, 32), dim3(256), 0, stream,
                     F, chunkOut, sc1, zreg);
  hipLaunchKernelGGL(chain1_kernel, dim3(4, 32), dim3(256), 0, stream,
                     chunkOut, sc1, levA, sc2, zreg);
  hipLaunchKernelGGL(final_kernel, dim3(B_), dim3(256), 0, stream,
                     p0buf, levA, sc2, tgtE, out);
}